// Round 6
// baseline (465.307 us; speedup 1.0000x reference)
//
#include <hip/hip_runtime.h>
#include <hip/hip_bf16.h>
#include <stdint.h>

#define NB 4
#define NN 2048
#define NF 128

typedef __attribute__((ext_vector_type(8))) short bf16x8;
typedef __attribute__((ext_vector_type(4))) short short4v;
typedef __attribute__((ext_vector_type(4))) float f32x4;

__device__ __forceinline__ short f2bf(float x) {
  __hip_bfloat16 h = __float2bfloat16(x);
  return *reinterpret_cast<short*>(&h);
}
__device__ __forceinline__ float bf2f(short s) {
  unsigned int u = ((unsigned int)(unsigned short)s) << 16;
  return __uint_as_float(u);
}

__device__ __forceinline__ void gload_lds16(void* lds, const void* g) {
  __builtin_amdgcn_global_load_lds(
      (const __attribute__((address_space(1))) unsigned int*)(uintptr_t)g,
      (__attribute__((address_space(3))) unsigned int*)(uintptr_t)lds,
      16, 0, 0);
}

// ---------------- Kernel 1: prep (rows) + misc (transpose/wt) in ONE launch ----------
// bid < 8192            : row degree -> dinv, Ab = bf16(adj); release flags[batch]
// bid 8192..8255        : wait flags[b]==2048, then hT0 = bf16((x*dinv)^T) tile
// bid 8256..8258        : wt = bf16(W^T)  (no dependency)
__global__ __launch_bounds__(256) void k_prepmisc(
    const float* __restrict__ adj, const float* __restrict__ x,
    const float* __restrict__ W1, const float* __restrict__ W2,
    const float* __restrict__ W3,
    float* __restrict__ dinv, short* __restrict__ Ab,
    short* __restrict__ xT, short* __restrict__ wt,
    unsigned* __restrict__ flags) {
  __shared__ short tile[128 * 129];     // used by transpose path (33 KB)
  __shared__ float red[4];
  const int bid = blockIdx.x;
  const int tid = threadIdx.x;

  if (bid < NB * NN) {
    // ---- prep: one row ----
    const int row = bid;
    const float* src = adj + (size_t)row * NN + tid * 8;
    const float4 v0 = *(const float4*)(src);
    const float4 v1 = *(const float4*)(src + 4);
    bf16x8 o;
    o[0] = f2bf(v0.x); o[1] = f2bf(v0.y); o[2] = f2bf(v0.z); o[3] = f2bf(v0.w);
    o[4] = f2bf(v1.x); o[5] = f2bf(v1.y); o[6] = f2bf(v1.z); o[7] = f2bf(v1.w);
    *(bf16x8*)(Ab + (size_t)row * NN + tid * 8) = o;
    float s = v0.x + v0.y + v0.z + v0.w + v1.x + v1.y + v1.z + v1.w;
    s += __shfl_xor(s, 1);  s += __shfl_xor(s, 2);  s += __shfl_xor(s, 4);
    s += __shfl_xor(s, 8);  s += __shfl_xor(s, 16); s += __shfl_xor(s, 32);
    const int w = tid >> 6, lane = tid & 63;
    if (lane == 0) red[w] = s;
    __syncthreads();
    if (tid == 0) {
      const float d = red[0] + red[1] + red[2] + red[3];
      dinv[row] = rsqrtf(d + 1e-6f);
      __threadfence();                   // dinv visible device-wide before release
      __hip_atomic_fetch_add(&flags[row >> 11], 1u,
                             __ATOMIC_RELEASE, __HIP_MEMORY_SCOPE_AGENT);
    }
  } else if (bid < NB * NN + 64) {
    // ---- transpose one [128 j][128 f] tile of x (scaled by dinv[j]) ----
    const int t = bid - NB * NN;
    const int b = t >> 4;
    const int j0 = (t & 15) << 7;
    if (tid == 0) {                      // load-spin (no RMW), 64 spinners total
      while (__hip_atomic_load(&flags[b], __ATOMIC_RELAXED,
                               __HIP_MEMORY_SCOPE_AGENT) < 2048u)
        __builtin_amdgcn_s_sleep(16);
    }
    __syncthreads();
    __threadfence();                     // acquire: see producers' dinv
#pragma unroll
    for (int r = 0; r < 8; ++r) {
      const int j = 16 * r + (tid >> 4);
      const int f0 = (tid & 15) * 8;
      const float sc = dinv[b * NN + j0 + j];
      const float4* p = (const float4*)(x + ((size_t)(b * NN + j0 + j)) * NF + f0);
      const float4 a0 = p[0], a1 = p[1];
      short* tt = tile + j * 129 + f0;
      tt[0] = f2bf(a0.x * sc); tt[1] = f2bf(a0.y * sc);
      tt[2] = f2bf(a0.z * sc); tt[3] = f2bf(a0.w * sc);
      tt[4] = f2bf(a1.x * sc); tt[5] = f2bf(a1.y * sc);
      tt[6] = f2bf(a1.z * sc); tt[7] = f2bf(a1.w * sc);
    }
    __syncthreads();
#pragma unroll
    for (int r = 0; r < 8; ++r) {
      const int f = 16 * r + (tid >> 4);
      const int jc = tid & 15;
      bf16x8 v;
#pragma unroll
      for (int q = 0; q < 8; ++q) v[q] = tile[(jc * 8 + q) * 129 + f];
      *(bf16x8*)(xT + ((size_t)(b * NF + f)) * NN + j0 + jc * 8) = v;
    }
  } else {
    // ---- wt conversion ----
    const int wl = bid - (NB * NN + 64);
    const float* W = (wl == 0) ? W1 : (wl == 1) ? W2 : W3;
#pragma unroll 4
    for (int r = 0; r < 64; ++r) {
      const int e = r * 256 + tid;
      const int o = e >> 7, f = e & 127;
      wt[wl * 16384 + e] = f2bf(W[f * NF + o]);   // wt[o][f] = W[f][o]
    }
  }
}

// ---------------- Kernel 2: fused layer ----------------
// y = A_raw @ h_scaled  (BM=32, BN=128, BK=128, 8 waves: 4 col-slices x 2 K-halves)
// 3-buffer counted-vmcnt pipeline; then z = dinv_i*(y @ W) + bias (stage-2 MFMA,
// y split hi/lo bf16), relu?, + resid. yp exchange padded to 132 f32/row
// (write 2-way, read 2-way banks -> free; was 4/16-way).
template <bool LAST>
__global__ __launch_bounds__(512) void k_agg2(const short* __restrict__ Ab,
                                              const float* __restrict__ dinv,
                                              const short* __restrict__ hT,
                                              const float* __restrict__ resid,
                                              const short* __restrict__ wT,
                                              const float* __restrict__ bias,
                                              float* __restrict__ outF,
                                              short* __restrict__ outT) {
  const int bid0 = blockIdx.x;
  const int bid = (bid0 & 7) * 32 + (bid0 >> 3);   // XCD-chunked swizzle (256 = 8*32)
  const int b = bid >> 6;
  const int i0 = (bid & 63) << 5;
  const int tid = threadIdx.x;
  const int w = tid >> 6, lane = tid & 63;
  const int lo = lane & 15, hi = lane >> 4;
  const int kg = w >> 2, wc = w & 3;

  __shared__ __align__(16) char lds[3][40960];   // per buf: A 32x128 (8K) + H 128x128 (32K)

  // stage-2 W fragments: B[k=f][n=o] from wT[o][f]
  bf16x8 wfrag[4];
#pragma unroll
  for (int ks = 0; ks < 4; ++ks)
    wfrag[ks] = *(const bf16x8*)(wT + (16 * w + lo) * NF + ks * 32 + hi * 8);
  // anchor: force wfrag loads to complete NOW so loop vmcnt bookkeeping is exact
  asm volatile("" :: "v"(wfrag[0]), "v"(wfrag[1]), "v"(wfrag[2]), "v"(wfrag[3]));

  // staging sources (pre-swizzled 16B chunk within each 256 B tile row)
  const int rA = tid >> 4, cA = tid & 15;
  const short* Asrc = Ab + (size_t)(b * NN + i0 + rA) * NN + ((cA ^ (rA & 7)) * 8);
  const short* Hsrc[4];
#pragma unroll
  for (int p = 0; p < 4; ++p) {
    const int c = tid + 512 * p;
    const int f = c >> 4, ch = c & 15;
    Hsrc[p] = hT + (size_t)(b * NF + f) * NN + ((ch ^ (f & 7)) * 8);
  }

  // fragment ds_read offsets (swizzled); wave kg reads k-elems [kg*64, kg*64+64)
  int offA[2][2], offH[2][2];
#pragma unroll
  for (int mm = 0; mm < 2; ++mm)
#pragma unroll
    for (int ks = 0; ks < 2; ++ks) {
      const int r = 16 * mm + lo;
      const int ck = kg * 8 + ks * 4 + hi;
      offA[mm][ks] = r * 256 + ((ck ^ (r & 7)) << 4);
    }
#pragma unroll
  for (int nn = 0; nn < 2; ++nn)
#pragma unroll
    for (int ks = 0; ks < 2; ++ks) {
      const int f = 32 * wc + 16 * nn + lo;
      const int ck = kg * 8 + ks * 4 + hi;
      offH[nn][ks] = 8192 + f * 256 + ((ck ^ (f & 7)) << 4);
    }

  f32x4 acc[2][2] = {};

#define STAGE_T(t_, base_)                                              \
  do {                                                                  \
    const int koff_ = (t_) * 128;                                       \
    char* nb_ = (base_);                                                \
    gload_lds16(nb_ + tid * 16, Asrc + koff_);                          \
    _Pragma("unroll")                                                   \
    for (int p_ = 0; p_ < 4; ++p_)                                      \
      gload_lds16(nb_ + 8192 + (tid + 512 * p_) * 16, Hsrc[p_] + koff_);\
  } while (0)

  // prologue: 2 tiles in flight (10 loads/thread)
  STAGE_T(0, lds[0]);
  STAGE_T(1, lds[1]);

  const int NT = NN / 128;               // 16 supersteps
  for (int t = 0; t < NT; ++t) {
    // wait for tile t (5 loads/thread of tile t+1 may remain in flight)
    if (t < NT - 1) asm volatile("s_waitcnt vmcnt(5)" ::: "memory");
    else            asm volatile("s_waitcnt vmcnt(0)" ::: "memory");
    asm volatile("s_barrier" ::: "memory");          // all waves' tile-t loads landed
    if (t + 2 < NT) STAGE_T(t + 2, lds[(t + 2) % 3]);  // overwrites t-1's buf (reads done)
    const char* buf = lds[t % 3];
    bf16x8 af[2][2], hf[2][2];
#pragma unroll
    for (int mm = 0; mm < 2; ++mm)
#pragma unroll
      for (int ks = 0; ks < 2; ++ks)
        af[mm][ks] = *(const bf16x8*)(buf + offA[mm][ks]);
#pragma unroll
    for (int nn = 0; nn < 2; ++nn)
#pragma unroll
      for (int ks = 0; ks < 2; ++ks)
        hf[nn][ks] = *(const bf16x8*)(buf + offH[nn][ks]);
#pragma unroll
    for (int ks = 0; ks < 2; ++ks)
#pragma unroll
      for (int mm = 0; mm < 2; ++mm)
#pragma unroll
        for (int nn = 0; nn < 2; ++nn)
          acc[mm][nn] = __builtin_amdgcn_mfma_f32_16x16x32_bf16(
              af[mm][ks], hf[nn][ks], acc[mm][nn], 0, 0, 0);
  }
#undef STAGE_T
  __syncthreads();                       // all tile-15 reads done before yp overwrite

  // ---- exchange: sum K-half partials, split y into bf16 hi+lo ----
  // yp rows padded to 132 f32 (528 B): both scatter-write and gather-read 2-way.
  float* yp = (float*)lds;               // [2][32][132] f32 = 33 KB
#pragma unroll
  for (int mm = 0; mm < 2; ++mm)
#pragma unroll
    for (int nn = 0; nn < 2; ++nn) {
      const int f = 32 * wc + 16 * nn + lo;
      const int ib = 16 * mm + hi * 4;
#pragma unroll
      for (int r = 0; r < 4; ++r)
        yp[kg * 4224 + (ib + r) * 132 + f] = acc[mm][nn][r];
    }
  __syncthreads();
  {
    const int ii = tid >> 4;             // 0..31
    const int fc = tid & 15;             // 16B chunk
    const float4 s0 = *(const float4*)(yp + ii * 132 + fc * 8);
    const float4 s1 = *(const float4*)(yp + ii * 132 + fc * 8 + 4);
    const float4 t0 = *(const float4*)(yp + 4224 + ii * 132 + fc * 8);
    const float4 t1 = *(const float4*)(yp + 4224 + ii * 132 + fc * 8 + 4);
    float v[8] = {s0.x + t0.x, s0.y + t0.y, s0.z + t0.z, s0.w + t0.w,
                  s1.x + t1.x, s1.y + t1.y, s1.z + t1.z, s1.w + t1.w};
    bf16x8 vh, vl;
#pragma unroll
    for (int q = 0; q < 8; ++q) {
      vh[q] = f2bf(v[q]);
      vl[q] = f2bf(v[q] - bf2f(vh[q]));
    }
    const int ch = fc ^ (ii & 7);
    *(bf16x8*)((char*)lds + 36864 + ii * 256 + ch * 16) = vh;
    *(bf16x8*)((char*)lds + 45056 + ii * 256 + ch * 16) = vl;
  }
  __syncthreads();

  // ---- stage 2: z = y @ W ; wave w owns o-cols [16w, 16w+16) ----
  f32x4 acc2[2] = {};
#pragma unroll
  for (int ks = 0; ks < 4; ++ks) {
#pragma unroll
    for (int mm = 0; mm < 2; ++mm) {
      const int r = 16 * mm + lo;
      const int ck = (ks * 4 + hi) ^ (r & 7);
      const bf16x8 ahi = *(const bf16x8*)((char*)lds + 36864 + r * 256 + (ck << 4));
      const bf16x8 alo = *(const bf16x8*)((char*)lds + 45056 + r * 256 + (ck << 4));
      acc2[mm] = __builtin_amdgcn_mfma_f32_16x16x32_bf16(ahi, wfrag[ks], acc2[mm], 0, 0, 0);
      acc2[mm] = __builtin_amdgcn_mfma_f32_16x16x32_bf16(alo, wfrag[ks], acc2[mm], 0, 0, 0);
    }
  }

  // ---- epilogue: z = dinv_i*acc2 + bias, relu?, + resid; write f32 (+ bf16^T) ----
  const int o = 16 * w + lo;
  const float bi = bias[o];
#pragma unroll
  for (int mm = 0; mm < 2; ++mm) {
    const int ib = i0 + 16 * mm + hi * 4;
    const float4 dv = *(const float4*)(dinv + b * NN + ib);
    const float dvr[4] = {dv.x, dv.y, dv.z, dv.w};
    float zr[4];
#pragma unroll
    for (int r = 0; r < 4; ++r) {
      float z = acc2[mm][r] * dvr[r] + bi;
      if (!LAST) z = fmaxf(z, 0.0f);
      const size_t idx = (size_t)(b * NN + ib + r) * NF + o;
      zr[r] = z + resid[idx];
      outF[idx] = zr[r];
    }
    if (!LAST) {
      short4v v;
#pragma unroll
      for (int r = 0; r < 4; ++r) v[r] = f2bf(zr[r] * dvr[r]);
      *(short4v*)(outT + (size_t)(b * NF + o) * NN + ib) = v;
    }
  }
}

extern "C" void kernel_launch(void* const* d_in, const int* in_sizes, int n_in,
                              void* d_out, int out_size, void* d_ws, size_t ws_size,
                              hipStream_t stream) {
  const float* x   = (const float*)d_in[0];
  const float* adj = (const float*)d_in[1];
  const float* W1  = (const float*)d_in[2];
  const float* b1  = (const float*)d_in[3];
  const float* W2  = (const float*)d_in[4];
  const float* b2  = (const float*)d_in[5];
  const float* W3  = (const float*)d_in[6];
  const float* b3  = (const float*)d_in[7];
  float* out = (float*)d_out;
  char* ws = (char*)d_ws;

  // workspace layout (bytes)
  float* dinv = (float*)(ws + 0);              // 32 KB
  short* wt   = (short*)(ws + 32768);          // 3 * 32 KB
  short* hT0  = (short*)(ws + 131072);         // 2 MB  (bf16 (x*dinv)^T)
  short* hT1  = (short*)(ws + 2228224);        // 2 MB
  short* hT2  = (short*)(ws + 4325376);        // 2 MB
  float* h1   = (float*)(ws + 6422528);        // 4 MB
  float* h2   = (float*)(ws + 10616832);       // 4 MB
  short* Ab   = (short*)(ws + 14811136);       // 32 MB (bf16 raw adj)
  unsigned* flags = (unsigned*)(ws + 48365568);

  hipMemsetAsync(flags, 0, 16, stream);
  k_prepmisc<<<NB * NN + 67, 256, 0, stream>>>(adj, x, W1, W2, W3,
                                               dinv, Ab, hT0, wt, flags);

  k_agg2<false><<<256, 512, 0, stream>>>(Ab, dinv, hT0, x,  wt,         b1, h1,  hT1);
  k_agg2<false><<<256, 512, 0, stream>>>(Ab, dinv, hT1, h1, wt + 16384, b2, h2,  hT2);
  k_agg2<true> <<<256, 512, 0, stream>>>(Ab, dinv, hT2, h2, wt + 32768, b3, out, nullptr);
}

// Round 7
// 64.617 us; speedup vs baseline: 7.2010x; 7.2010x over previous
//
#include <hip/hip_runtime.h>
#include <hip/hip_bf16.h>
#include <stdint.h>

#define NB 4
#define NN 2048
#define NF 128

typedef __attribute__((ext_vector_type(8))) short bf16x8;
typedef __attribute__((ext_vector_type(4))) short short4v;
typedef __attribute__((ext_vector_type(4))) float f32x4;

__device__ __forceinline__ short f2bf(float x) {
  __hip_bfloat16 h = __float2bfloat16(x);
  return *reinterpret_cast<short*>(&h);
}
__device__ __forceinline__ float bf2f(short s) {
  unsigned int u = ((unsigned int)(unsigned short)s) << 16;
  return __uint_as_float(u);
}

__device__ __forceinline__ void gload_lds16(void* lds, const void* g) {
  __builtin_amdgcn_global_load_lds(
      (const __attribute__((address_space(1))) unsigned int*)(uintptr_t)g,
      (__attribute__((address_space(3))) unsigned int*)(uintptr_t)lds,
      16, 0, 0);
}

// ---------------- Kernel 1: prep — row degree -> dinv, and Ab = bf16(adj) ----------------
__global__ __launch_bounds__(256) void k_prep(const float* __restrict__ adj,
                                              float* __restrict__ dinv,
                                              short* __restrict__ Ab) {
  const int row = blockIdx.x;          // 0 .. NB*NN-1
  const int tid = threadIdx.x;
  const float* src = adj + (size_t)row * NN + tid * 8;
  const float4 v0 = *(const float4*)(src);
  const float4 v1 = *(const float4*)(src + 4);
  bf16x8 o;
  o[0] = f2bf(v0.x); o[1] = f2bf(v0.y); o[2] = f2bf(v0.z); o[3] = f2bf(v0.w);
  o[4] = f2bf(v1.x); o[5] = f2bf(v1.y); o[6] = f2bf(v1.z); o[7] = f2bf(v1.w);
  *(bf16x8*)(Ab + (size_t)row * NN + tid * 8) = o;
  float s = v0.x + v0.y + v0.z + v0.w + v1.x + v1.y + v1.z + v1.w;
  s += __shfl_xor(s, 1);  s += __shfl_xor(s, 2);  s += __shfl_xor(s, 4);
  s += __shfl_xor(s, 8);  s += __shfl_xor(s, 16); s += __shfl_xor(s, 32);
  __shared__ float red[4];
  const int w = tid >> 6, lane = tid & 63;
  if (lane == 0) red[w] = s;
  __syncthreads();
  if (tid == 0) {
    const float d = red[0] + red[1] + red[2] + red[3];
    dinv[row] = rsqrtf(d + 1e-6f);
  }
}

// ---------------- Kernel 2: misc — hT0 = bf16((x*dinv_j)^T) (blocks 0..63), wt (64..66) ----
__global__ __launch_bounds__(256) void k_misc(const float* __restrict__ x,
                                              const float* __restrict__ W1,
                                              const float* __restrict__ W2,
                                              const float* __restrict__ W3,
                                              const float* __restrict__ dinv,
                                              short* __restrict__ xT,
                                              short* __restrict__ wt) {
  const int bid = blockIdx.x;
  const int tid = threadIdx.x;
  if (bid < 64) {
    const int b = bid >> 4;
    const int j0 = (bid & 15) << 7;
    __shared__ short tile[128 * 129];
#pragma unroll
    for (int r = 0; r < 8; ++r) {
      const int j = 16 * r + (tid >> 4);
      const int f0 = (tid & 15) * 8;
      const float sc = dinv[b * NN + j0 + j];
      const float4* p = (const float4*)(x + ((size_t)(b * NN + j0 + j)) * NF + f0);
      const float4 a0 = p[0], a1 = p[1];
      short* t = tile + j * 129 + f0;
      t[0] = f2bf(a0.x * sc); t[1] = f2bf(a0.y * sc);
      t[2] = f2bf(a0.z * sc); t[3] = f2bf(a0.w * sc);
      t[4] = f2bf(a1.x * sc); t[5] = f2bf(a1.y * sc);
      t[6] = f2bf(a1.z * sc); t[7] = f2bf(a1.w * sc);
    }
    __syncthreads();
#pragma unroll
    for (int r = 0; r < 8; ++r) {
      const int f = 16 * r + (tid >> 4);
      const int jc = tid & 15;
      bf16x8 v;
#pragma unroll
      for (int q = 0; q < 8; ++q) v[q] = tile[(jc * 8 + q) * 129 + f];
      *(bf16x8*)(xT + ((size_t)(b * NF + f)) * NN + j0 + jc * 8) = v;
    }
  } else {
    const int wl = bid - 64;
    const float* W = (wl == 0) ? W1 : (wl == 1) ? W2 : W3;
#pragma unroll 4
    for (int r = 0; r < 64; ++r) {
      const int e = r * 256 + tid;
      const int o = e >> 7, f = e & 127;
      wt[wl * 16384 + e] = f2bf(W[f * NF + o]);   // wt[o][f] = W[f][o]
    }
  }
}

// ---------------- Kernel 3: fused layer ----------------
// y = A_raw @ h_scaled  (BM=32, BN=128, BK=128, 8 waves: 4 col-slices x 2 K-halves)
// 3-buffer counted-vmcnt pipeline; then z = dinv_i*(y @ W) + bias (stage-2 MFMA,
// y split hi/lo bf16), relu?, + resid. yp exchange rows padded to 132 f32
// (write 2-way, read 2-way banks -> free; was 4/16-way).
template <bool LAST>
__global__ __launch_bounds__(512) void k_agg2(const short* __restrict__ Ab,
                                              const float* __restrict__ dinv,
                                              const short* __restrict__ hT,
                                              const float* __restrict__ resid,
                                              const short* __restrict__ wT,
                                              const float* __restrict__ bias,
                                              float* __restrict__ outF,
                                              short* __restrict__ outT) {
  const int bid0 = blockIdx.x;
  const int bid = (bid0 & 7) * 32 + (bid0 >> 3);   // XCD-chunked swizzle (256 = 8*32)
  const int b = bid >> 6;
  const int i0 = (bid & 63) << 5;
  const int tid = threadIdx.x;
  const int w = tid >> 6, lane = tid & 63;
  const int lo = lane & 15, hi = lane >> 4;
  const int kg = w >> 2, wc = w & 3;

  __shared__ __align__(16) char lds[3][40960];   // per buf: A 32x128 (8K) + H 128x128 (32K)

  // stage-2 W fragments: B[k=f][n=o] from wT[o][f]
  bf16x8 wfrag[4];
#pragma unroll
  for (int ks = 0; ks < 4; ++ks)
    wfrag[ks] = *(const bf16x8*)(wT + (16 * w + lo) * NF + ks * 32 + hi * 8);
  // anchor: force wfrag loads to complete NOW so loop vmcnt bookkeeping is exact
  asm volatile("" :: "v"(wfrag[0]), "v"(wfrag[1]), "v"(wfrag[2]), "v"(wfrag[3]));

  // staging sources (pre-swizzled 16B chunk within each 256 B tile row)
  const int rA = tid >> 4, cA = tid & 15;
  const short* Asrc = Ab + (size_t)(b * NN + i0 + rA) * NN + ((cA ^ (rA & 7)) * 8);
  const short* Hsrc[4];
#pragma unroll
  for (int p = 0; p < 4; ++p) {
    const int c = tid + 512 * p;
    const int f = c >> 4, ch = c & 15;
    Hsrc[p] = hT + (size_t)(b * NF + f) * NN + ((ch ^ (f & 7)) * 8);
  }

  // fragment ds_read offsets (swizzled); wave kg reads k-elems [kg*64, kg*64+64)
  int offA[2][2], offH[2][2];
#pragma unroll
  for (int mm = 0; mm < 2; ++mm)
#pragma unroll
    for (int ks = 0; ks < 2; ++ks) {
      const int r = 16 * mm + lo;
      const int ck = kg * 8 + ks * 4 + hi;
      offA[mm][ks] = r * 256 + ((ck ^ (r & 7)) << 4);
    }
#pragma unroll
  for (int nn = 0; nn < 2; ++nn)
#pragma unroll
    for (int ks = 0; ks < 2; ++ks) {
      const int f = 32 * wc + 16 * nn + lo;
      const int ck = kg * 8 + ks * 4 + hi;
      offH[nn][ks] = 8192 + f * 256 + ((ck ^ (f & 7)) << 4);
    }

  f32x4 acc[2][2] = {};

#define STAGE_T(t_, base_)                                              \
  do {                                                                  \
    const int koff_ = (t_) * 128;                                       \
    char* nb_ = (base_);                                                \
    gload_lds16(nb_ + tid * 16, Asrc + koff_);                          \
    _Pragma("unroll")                                                   \
    for (int p_ = 0; p_ < 4; ++p_)                                      \
      gload_lds16(nb_ + 8192 + (tid + 512 * p_) * 16, Hsrc[p_] + koff_);\
  } while (0)

  // prologue: 2 tiles in flight (10 loads/thread)
  STAGE_T(0, lds[0]);
  STAGE_T(1, lds[1]);

  const int NT = NN / 128;               // 16 supersteps
  for (int t = 0; t < NT; ++t) {
    // wait for tile t (5 loads/thread of tile t+1 may remain in flight)
    if (t < NT - 1) asm volatile("s_waitcnt vmcnt(5)" ::: "memory");
    else            asm volatile("s_waitcnt vmcnt(0)" ::: "memory");
    asm volatile("s_barrier" ::: "memory");          // all waves' tile-t loads landed
    if (t + 2 < NT) STAGE_T(t + 2, lds[(t + 2) % 3]);  // overwrites t-1's buf (reads done)
    const char* buf = lds[t % 3];
    bf16x8 af[2][2], hf[2][2];
#pragma unroll
    for (int mm = 0; mm < 2; ++mm)
#pragma unroll
      for (int ks = 0; ks < 2; ++ks)
        af[mm][ks] = *(const bf16x8*)(buf + offA[mm][ks]);
#pragma unroll
    for (int nn = 0; nn < 2; ++nn)
#pragma unroll
      for (int ks = 0; ks < 2; ++ks)
        hf[nn][ks] = *(const bf16x8*)(buf + offH[nn][ks]);
#pragma unroll
    for (int ks = 0; ks < 2; ++ks)
#pragma unroll
      for (int mm = 0; mm < 2; ++mm)
#pragma unroll
        for (int nn = 0; nn < 2; ++nn)
          acc[mm][nn] = __builtin_amdgcn_mfma_f32_16x16x32_bf16(
              af[mm][ks], hf[nn][ks], acc[mm][nn], 0, 0, 0);
  }
#undef STAGE_T
  __syncthreads();                       // all tile-15 reads done before yp overwrite

  // ---- exchange: sum K-half partials, split y into bf16 hi+lo ----
  // yp rows padded to 132 f32 (528 B): both scatter-write and gather-read 2-way.
  float* yp = (float*)lds;               // [2][32][132] f32 = 33 KB
#pragma unroll
  for (int mm = 0; mm < 2; ++mm)
#pragma unroll
    for (int nn = 0; nn < 2; ++nn) {
      const int f = 32 * wc + 16 * nn + lo;
      const int ib = 16 * mm + hi * 4;
#pragma unroll
      for (int r = 0; r < 4; ++r)
        yp[kg * 4224 + (ib + r) * 132 + f] = acc[mm][nn][r];
    }
  __syncthreads();
  {
    const int ii = tid >> 4;             // 0..31
    const int fc = tid & 15;             // 16B chunk
    const float4 s0 = *(const float4*)(yp + ii * 132 + fc * 8);
    const float4 s1 = *(const float4*)(yp + ii * 132 + fc * 8 + 4);
    const float4 t0 = *(const float4*)(yp + 4224 + ii * 132 + fc * 8);
    const float4 t1 = *(const float4*)(yp + 4224 + ii * 132 + fc * 8 + 4);
    float v[8] = {s0.x + t0.x, s0.y + t0.y, s0.z + t0.z, s0.w + t0.w,
                  s1.x + t1.x, s1.y + t1.y, s1.z + t1.z, s1.w + t1.w};
    bf16x8 vh, vl;
#pragma unroll
    for (int q = 0; q < 8; ++q) {
      vh[q] = f2bf(v[q]);
      vl[q] = f2bf(v[q] - bf2f(vh[q]));
    }
    const int ch = fc ^ (ii & 7);
    *(bf16x8*)((char*)lds + 36864 + ii * 256 + ch * 16) = vh;
    *(bf16x8*)((char*)lds + 45056 + ii * 256 + ch * 16) = vl;
  }
  __syncthreads();

  // ---- stage 2: z = y @ W ; wave w owns o-cols [16w, 16w+16) ----
  f32x4 acc2[2] = {};
#pragma unroll
  for (int ks = 0; ks < 4; ++ks) {
#pragma unroll
    for (int mm = 0; mm < 2; ++mm) {
      const int r = 16 * mm + lo;
      const int ck = (ks * 4 + hi) ^ (r & 7);
      const bf16x8 ahi = *(const bf16x8*)((char*)lds + 36864 + r * 256 + (ck << 4));
      const bf16x8 alo = *(const bf16x8*)((char*)lds + 45056 + r * 256 + (ck << 4));
      acc2[mm] = __builtin_amdgcn_mfma_f32_16x16x32_bf16(ahi, wfrag[ks], acc2[mm], 0, 0, 0);
      acc2[mm] = __builtin_amdgcn_mfma_f32_16x16x32_bf16(alo, wfrag[ks], acc2[mm], 0, 0, 0);
    }
  }

  // ---- epilogue: z = dinv_i*acc2 + bias, relu?, + resid; write f32 (+ bf16^T) ----
  const int o = 16 * w + lo;
  const float bi = bias[o];
#pragma unroll
  for (int mm = 0; mm < 2; ++mm) {
    const int ib = i0 + 16 * mm + hi * 4;
    const float4 dv = *(const float4*)(dinv + b * NN + ib);
    const float dvr[4] = {dv.x, dv.y, dv.z, dv.w};
    float zr[4];
#pragma unroll
    for (int r = 0; r < 4; ++r) {
      float z = acc2[mm][r] * dvr[r] + bi;
      if (!LAST) z = fmaxf(z, 0.0f);
      const size_t idx = (size_t)(b * NN + ib + r) * NF + o;
      zr[r] = z + resid[idx];
      outF[idx] = zr[r];
    }
    if (!LAST) {
      short4v v;
#pragma unroll
      for (int r = 0; r < 4; ++r) v[r] = f2bf(zr[r] * dvr[r]);
      *(short4v*)(outT + (size_t)(b * NF + o) * NN + ib) = v;
    }
  }
}

extern "C" void kernel_launch(void* const* d_in, const int* in_sizes, int n_in,
                              void* d_out, int out_size, void* d_ws, size_t ws_size,
                              hipStream_t stream) {
  const float* x   = (const float*)d_in[0];
  const float* adj = (const float*)d_in[1];
  const float* W1  = (const float*)d_in[2];
  const float* b1  = (const float*)d_in[3];
  const float* W2  = (const float*)d_in[4];
  const float* b2  = (const float*)d_in[5];
  const float* W3  = (const float*)d_in[6];
  const float* b3  = (const float*)d_in[7];
  float* out = (float*)d_out;
  char* ws = (char*)d_ws;

  // workspace layout (bytes)
  float* dinv = (float*)(ws + 0);              // 32 KB
  short* wt   = (short*)(ws + 32768);          // 3 * 32 KB
  short* hT0  = (short*)(ws + 131072);         // 2 MB  (bf16 (x*dinv)^T)
  short* hT1  = (short*)(ws + 2228224);        // 2 MB
  short* hT2  = (short*)(ws + 4325376);        // 2 MB
  float* h1   = (float*)(ws + 6422528);        // 4 MB
  float* h2   = (float*)(ws + 10616832);       // 4 MB
  short* Ab   = (short*)(ws + 14811136);       // 32 MB (bf16 raw adj)

  k_prep<<<NB * NN, 256, 0, stream>>>(adj, dinv, Ab);
  k_misc<<<67, 256, 0, stream>>>(x, W1, W2, W3, dinv, hT0, wt);

  k_agg2<false><<<256, 512, 0, stream>>>(Ab, dinv, hT0, x,  wt,         b1, h1,  hT1);
  k_agg2<false><<<256, 512, 0, stream>>>(Ab, dinv, hT1, h1, wt + 16384, b2, h2,  hT2);
  k_agg2<true> <<<256, 512, 0, stream>>>(Ab, dinv, hT2, h2, wt + 32768, b3, out, nullptr);
}

// Round 8
// 62.961 us; speedup vs baseline: 7.3904x; 1.0263x over previous
//
#include <hip/hip_runtime.h>
#include <hip/hip_bf16.h>
#include <stdint.h>

#define NB 4
#define NN 2048
#define NF 128

typedef __attribute__((ext_vector_type(8))) short bf16x8;
typedef __attribute__((ext_vector_type(4))) short short4v;
typedef __attribute__((ext_vector_type(4))) float f32x4;

__device__ __forceinline__ short f2bf(float x) {
  __hip_bfloat16 h = __float2bfloat16(x);
  return *reinterpret_cast<short*>(&h);
}
__device__ __forceinline__ float bf2f(short s) {
  unsigned int u = ((unsigned int)(unsigned short)s) << 16;
  return __uint_as_float(u);
}

__device__ __forceinline__ void gload_lds16(void* lds, const void* g) {
  __builtin_amdgcn_global_load_lds(
      (const __attribute__((address_space(1))) unsigned int*)(uintptr_t)g,
      (__attribute__((address_space(3))) unsigned int*)(uintptr_t)lds,
      16, 0, 0);
}

// ---------------- Kernel 1: prep — 8 rows/block: dinv, Ab = bf16(adj),
//                  hT0 = bf16((x*dinv)^T) slice; blocks 1024..1026: wt = bf16(W^T).
// All block-local (dinv for a block's 8 rows computed in-block) — NO cross-block sync.
__global__ __launch_bounds__(256) void k_prep(
    const float* __restrict__ adj, const float* __restrict__ x,
    const float* __restrict__ W1, const float* __restrict__ W2,
    const float* __restrict__ W3,
    float* __restrict__ dinv, short* __restrict__ Ab,
    short* __restrict__ hT0, short* __restrict__ wt) {
  const int bid = blockIdx.x;
  const int tid = threadIdx.x;
  if (bid < 1024) {
    __shared__ float srows[8][4];
    __shared__ float sdv[8];
    __shared__ short tileT[128 * 9];     // [f][j] with +1 pad
    const int r0 = bid * 8;              // global row base
    const int b = r0 >> 11;
    const int j0 = r0 - b * NN;          // within-batch column base for hT0
    const int w = tid >> 6, lane = tid & 63;

    // ---- adj pass: 8 rows, convert + row-sum ----
#pragma unroll
    for (int rr = 0; rr < 8; ++rr) {
      const int row = r0 + rr;
      const float* src = adj + (size_t)row * NN + tid * 8;
      const float4 v0 = *(const float4*)(src);
      const float4 v1 = *(const float4*)(src + 4);
      bf16x8 o;
      o[0] = f2bf(v0.x); o[1] = f2bf(v0.y); o[2] = f2bf(v0.z); o[3] = f2bf(v0.w);
      o[4] = f2bf(v1.x); o[5] = f2bf(v1.y); o[6] = f2bf(v1.z); o[7] = f2bf(v1.w);
      *(bf16x8*)(Ab + (size_t)row * NN + tid * 8) = o;
      float s = v0.x + v0.y + v0.z + v0.w + v1.x + v1.y + v1.z + v1.w;
      s += __shfl_xor(s, 1);  s += __shfl_xor(s, 2);  s += __shfl_xor(s, 4);
      s += __shfl_xor(s, 8);  s += __shfl_xor(s, 16); s += __shfl_xor(s, 32);
      if (lane == 0) srows[rr][w] = s;
    }
    __syncthreads();
    if (tid < 8) {
      const float d = srows[tid][0] + srows[tid][1] + srows[tid][2] + srows[tid][3];
      const float dv = rsqrtf(d + 1e-6f);
      dinv[r0 + tid] = dv;
      sdv[tid] = dv;
    }
    __syncthreads();

    // ---- x pass: scale 8 rows by dinv, transpose into LDS ----
    {
      const int rr = tid >> 5;           // 0..7 (row)
      const int c = tid & 31;            // 0..31 (4 f each)
      const float sc = sdv[rr];
      const float4 xv = *(const float4*)(x + (size_t)(r0 + rr) * NF + c * 4);
      tileT[(c * 4 + 0) * 9 + rr] = f2bf(xv.x * sc);
      tileT[(c * 4 + 1) * 9 + rr] = f2bf(xv.y * sc);
      tileT[(c * 4 + 2) * 9 + rr] = f2bf(xv.z * sc);
      tileT[(c * 4 + 3) * 9 + rr] = f2bf(xv.w * sc);
    }
    __syncthreads();
    if (tid < 128) {                     // f = tid: write 8-j slice, 16 B coalesced
      bf16x8 v;
#pragma unroll
      for (int q = 0; q < 8; ++q) v[q] = tileT[tid * 9 + q];
      *(bf16x8*)(hT0 + ((size_t)(b * NF + tid)) * NN + j0) = v;
    }
  } else {
    // ---- wt conversion (independent) ----
    const int wl = bid - 1024;
    const float* W = (wl == 0) ? W1 : (wl == 1) ? W2 : W3;
#pragma unroll 4
    for (int r = 0; r < 64; ++r) {
      const int e = r * 256 + tid;
      const int o = e >> 7, f = e & 127;
      wt[wl * 16384 + e] = f2bf(W[f * NF + o]);   // wt[o][f] = W[f][o]
    }
  }
}

// ---------------- Kernel 2: fused layer ----------------
// y = A_raw @ h_scaled  (BM=32, BN=128, BK=128, 8 waves: 4 col-slices x 2 K-halves)
// 3-buffer counted-vmcnt pipeline; then z = dinv_i*(y @ W) + bias (stage-2 MFMA,
// y split hi/lo bf16), relu?, + resid. yp exchange rows padded to 132 f32.
template <bool LAST>
__global__ __launch_bounds__(512) void k_agg2(const short* __restrict__ Ab,
                                              const float* __restrict__ dinv,
                                              const short* __restrict__ hT,
                                              const float* __restrict__ resid,
                                              const short* __restrict__ wT,
                                              const float* __restrict__ bias,
                                              float* __restrict__ outF,
                                              short* __restrict__ outT) {
  const int bid0 = blockIdx.x;
  const int bid = (bid0 & 7) * 32 + (bid0 >> 3);   // XCD-chunked swizzle (256 = 8*32)
  const int b = bid >> 6;
  const int i0 = (bid & 63) << 5;
  const int tid = threadIdx.x;
  const int w = tid >> 6, lane = tid & 63;
  const int lo = lane & 15, hi = lane >> 4;
  const int kg = w >> 2, wc = w & 3;

  __shared__ __align__(16) char lds[3][40960];   // per buf: A 32x128 (8K) + H 128x128 (32K)

  // stage-2 W fragments: B[k=f][n=o] from wT[o][f]
  bf16x8 wfrag[4];
#pragma unroll
  for (int ks = 0; ks < 4; ++ks)
    wfrag[ks] = *(const bf16x8*)(wT + (16 * w + lo) * NF + ks * 32 + hi * 8);
  // anchor: force wfrag loads to complete NOW so loop vmcnt bookkeeping is exact
  asm volatile("" :: "v"(wfrag[0]), "v"(wfrag[1]), "v"(wfrag[2]), "v"(wfrag[3]));

  // staging sources (pre-swizzled 16B chunk within each 256 B tile row)
  const int rA = tid >> 4, cA = tid & 15;
  const short* Asrc = Ab + (size_t)(b * NN + i0 + rA) * NN + ((cA ^ (rA & 7)) * 8);
  const short* Hsrc[4];
#pragma unroll
  for (int p = 0; p < 4; ++p) {
    const int c = tid + 512 * p;
    const int f = c >> 4, ch = c & 15;
    Hsrc[p] = hT + (size_t)(b * NF + f) * NN + ((ch ^ (f & 7)) * 8);
  }

  // fragment ds_read offsets (swizzled); wave kg reads k-elems [kg*64, kg*64+64)
  int offA[2][2], offH[2][2];
#pragma unroll
  for (int mm = 0; mm < 2; ++mm)
#pragma unroll
    for (int ks = 0; ks < 2; ++ks) {
      const int r = 16 * mm + lo;
      const int ck = kg * 8 + ks * 4 + hi;
      offA[mm][ks] = r * 256 + ((ck ^ (r & 7)) << 4);
    }
#pragma unroll
  for (int nn = 0; nn < 2; ++nn)
#pragma unroll
    for (int ks = 0; ks < 2; ++ks) {
      const int f = 32 * wc + 16 * nn + lo;
      const int ck = kg * 8 + ks * 4 + hi;
      offH[nn][ks] = 8192 + f * 256 + ((ck ^ (f & 7)) << 4);
    }

  f32x4 acc[2][2] = {};

#define STAGE_T(t_, base_)                                              \
  do {                                                                  \
    const int koff_ = (t_) * 128;                                       \
    char* nb_ = (base_);                                                \
    gload_lds16(nb_ + tid * 16, Asrc + koff_);                          \
    _Pragma("unroll")                                                   \
    for (int p_ = 0; p_ < 4; ++p_)                                      \
      gload_lds16(nb_ + 8192 + (tid + 512 * p_) * 16, Hsrc[p_] + koff_);\
  } while (0)

  // prologue: 2 tiles in flight (10 loads/thread)
  STAGE_T(0, lds[0]);
  STAGE_T(1, lds[1]);

  const int NT = NN / 128;               // 16 supersteps
  for (int t = 0; t < NT; ++t) {
    // wait for tile t (5 loads/thread of tile t+1 may remain in flight)
    if (t < NT - 1) asm volatile("s_waitcnt vmcnt(5)" ::: "memory");
    else            asm volatile("s_waitcnt vmcnt(0)" ::: "memory");
    asm volatile("s_barrier" ::: "memory");          // all waves' tile-t loads landed
    if (t + 2 < NT) STAGE_T(t + 2, lds[(t + 2) % 3]);  // overwrites t-1's buf (reads done)
    const char* buf = lds[t % 3];
    bf16x8 af[2][2], hf[2][2];
#pragma unroll
    for (int mm = 0; mm < 2; ++mm)
#pragma unroll
      for (int ks = 0; ks < 2; ++ks)
        af[mm][ks] = *(const bf16x8*)(buf + offA[mm][ks]);
#pragma unroll
    for (int nn = 0; nn < 2; ++nn)
#pragma unroll
      for (int ks = 0; ks < 2; ++ks)
        hf[nn][ks] = *(const bf16x8*)(buf + offH[nn][ks]);
#pragma unroll
    for (int ks = 0; ks < 2; ++ks)
#pragma unroll
      for (int mm = 0; mm < 2; ++mm)
#pragma unroll
        for (int nn = 0; nn < 2; ++nn)
          acc[mm][nn] = __builtin_amdgcn_mfma_f32_16x16x32_bf16(
              af[mm][ks], hf[nn][ks], acc[mm][nn], 0, 0, 0);
  }
#undef STAGE_T
  __syncthreads();                       // all tile-15 reads done before yp overwrite

  // ---- exchange: sum K-half partials, split y into bf16 hi+lo ----
  float* yp = (float*)lds;               // [2][32][132] f32 = 33 KB
#pragma unroll
  for (int mm = 0; mm < 2; ++mm)
#pragma unroll
    for (int nn = 0; nn < 2; ++nn) {
      const int f = 32 * wc + 16 * nn + lo;
      const int ib = 16 * mm + hi * 4;
#pragma unroll
      for (int r = 0; r < 4; ++r)
        yp[kg * 4224 + (ib + r) * 132 + f] = acc[mm][nn][r];
    }
  __syncthreads();
  {
    const int ii = tid >> 4;             // 0..31
    const int fc = tid & 15;             // 16B chunk
    const float4 s0 = *(const float4*)(yp + ii * 132 + fc * 8);
    const float4 s1 = *(const float4*)(yp + ii * 132 + fc * 8 + 4);
    const float4 t0 = *(const float4*)(yp + 4224 + ii * 132 + fc * 8);
    const float4 t1 = *(const float4*)(yp + 4224 + ii * 132 + fc * 8 + 4);
    float v[8] = {s0.x + t0.x, s0.y + t0.y, s0.z + t0.z, s0.w + t0.w,
                  s1.x + t1.x, s1.y + t1.y, s1.z + t1.z, s1.w + t1.w};
    bf16x8 vh, vl;
#pragma unroll
    for (int q = 0; q < 8; ++q) {
      vh[q] = f2bf(v[q]);
      vl[q] = f2bf(v[q] - bf2f(vh[q]));
    }
    const int ch = fc ^ (ii & 7);
    *(bf16x8*)((char*)lds + 36864 + ii * 256 + ch * 16) = vh;
    *(bf16x8*)((char*)lds + 45056 + ii * 256 + ch * 16) = vl;
  }
  __syncthreads();

  // ---- stage 2: z = y @ W ; wave w owns o-cols [16w, 16w+16) ----
  f32x4 acc2[2] = {};
#pragma unroll
  for (int ks = 0; ks < 4; ++ks) {
#pragma unroll
    for (int mm = 0; mm < 2; ++mm) {
      const int r = 16 * mm + lo;
      const int ck = (ks * 4 + hi) ^ (r & 7);
      const bf16x8 ahi = *(const bf16x8*)((char*)lds + 36864 + r * 256 + (ck << 4));
      const bf16x8 alo = *(const bf16x8*)((char*)lds + 45056 + r * 256 + (ck << 4));
      acc2[mm] = __builtin_amdgcn_mfma_f32_16x16x32_bf16(ahi, wfrag[ks], acc2[mm], 0, 0, 0);
      acc2[mm] = __builtin_amdgcn_mfma_f32_16x16x32_bf16(alo, wfrag[ks], acc2[mm], 0, 0, 0);
    }
  }

  // ---- epilogue: z = dinv_i*acc2 + bias, relu?, + resid; write f32 (+ bf16^T) ----
  const int o = 16 * w + lo;
  const float bi = bias[o];
#pragma unroll
  for (int mm = 0; mm < 2; ++mm) {
    const int ib = i0 + 16 * mm + hi * 4;
    const float4 dv = *(const float4*)(dinv + b * NN + ib);
    const float dvr[4] = {dv.x, dv.y, dv.z, dv.w};
    float zr[4];
#pragma unroll
    for (int r = 0; r < 4; ++r) {
      float z = acc2[mm][r] * dvr[r] + bi;
      if (!LAST) z = fmaxf(z, 0.0f);
      const size_t idx = (size_t)(b * NN + ib + r) * NF + o;
      zr[r] = z + resid[idx];
      outF[idx] = zr[r];
    }
    if (!LAST) {
      short4v v;
#pragma unroll
      for (int r = 0; r < 4; ++r) v[r] = f2bf(zr[r] * dvr[r]);
      *(short4v*)(outT + (size_t)(b * NF + o) * NN + ib) = v;
    }
  }
}

extern "C" void kernel_launch(void* const* d_in, const int* in_sizes, int n_in,
                              void* d_out, int out_size, void* d_ws, size_t ws_size,
                              hipStream_t stream) {
  const float* x   = (const float*)d_in[0];
  const float* adj = (const float*)d_in[1];
  const float* W1  = (const float*)d_in[2];
  const float* b1  = (const float*)d_in[3];
  const float* W2  = (const float*)d_in[4];
  const float* b2  = (const float*)d_in[5];
  const float* W3  = (const float*)d_in[6];
  const float* b3  = (const float*)d_in[7];
  float* out = (float*)d_out;
  char* ws = (char*)d_ws;

  // workspace layout (bytes)
  float* dinv = (float*)(ws + 0);              // 32 KB
  short* wt   = (short*)(ws + 32768);          // 3 * 32 KB
  short* hT0  = (short*)(ws + 131072);         // 2 MB  (bf16 (x*dinv)^T)
  short* hT1  = (short*)(ws + 2228224);        // 2 MB
  short* hT2  = (short*)(ws + 4325376);        // 2 MB
  float* h1   = (float*)(ws + 6422528);        // 4 MB
  float* h2   = (float*)(ws + 10616832);       // 4 MB
  short* Ab   = (short*)(ws + 14811136);       // 32 MB (bf16 raw adj)

  k_prep<<<1027, 256, 0, stream>>>(adj, x, W1, W2, W3, dinv, Ab, hT0, wt);

  k_agg2<false><<<256, 512, 0, stream>>>(Ab, dinv, hT0, x,  wt,         b1, h1,  hT1);
  k_agg2<false><<<256, 512, 0, stream>>>(Ab, dinv, hT1, h1, wt + 16384, b2, h2,  hT2);
  k_agg2<true> <<<256, 512, 0, stream>>>(Ab, dinv, hT2, h2, wt + 32768, b3, out, nullptr);
}